// Round 6
// baseline (68.839 us; speedup 1.0000x reference)
//
#include <hip/hip_runtime.h>
#include <hip/hip_bf16.h>
#include <hip/hip_cooperative_groups.h>

namespace cg = cooperative_groups;

#define BATCH 4096
#define FEAT  64
#define LW    64
#define KH    5
#define KW    9
#define RH    5
#define PADL  4
#define NPOS  41   // p = h*KW+ww, 0..40; p>=41 (h==4, ww>=5) masked to zero
#define NW    16   // waves per block (K-split)

typedef __attribute__((ext_vector_type(8))) short bf16x8;
typedef __attribute__((ext_vector_type(4))) float f32x4;

__device__ __forceinline__ short f2bf(float x) {
    union { float f; unsigned u; } v; v.f = x;
    unsigned r = v.u + 0x7FFFu + ((v.u >> 16) & 1u);  // RNE
    return (short)(r >> 16);
}

__device__ __forceinline__ bf16x8 cvt8(f32x4 x0, f32x4 x1) {
    union { bf16x8 v; __hip_bfloat162 h[4]; } u;
    u.h[0] = __float22bfloat162_rn(float2{x0[0], x0[1]});
    u.h[1] = __float22bfloat162_rn(float2{x0[2], x0[3]});
    u.h[2] = __float22bfloat162_rn(float2{x1[0], x1[1]});
    u.h[3] = __float22bfloat162_rn(float2{x1[2], x1[3]});
    return u.v;
}

// Phase-B inner loop: B-fragments are 16B contiguous bf16 loads from Wt
// (R2/R3-verified addressing), A direct f32x4 loads + packed cvt (R5-proven).
template<int W>
__device__ __forceinline__ void chunk(
    const float* __restrict__ inputs, const float* __restrict__ cache,
    const short* __restrict__ Wt,
    int r0, int index_w, bool upd, bool shift, int n, int g,
    f32x4 acc[4])
{
    constexpr int P0 = (NPOS * W) / NW;
    constexpr int P1 = (NPOS * (W + 1)) / NW;

    const long b = r0 + n;
    const float* crow  = cache  + b * (RH * LW * FEAT);
    const float* inrow = inputs + b * FEAT;
    const int k0 = g * 8;

    #pragma unroll
    for (int p = P0; p < P1; ++p) {
        const int h = p / KW, ww = p % KW;               // compile-time
        const int col = index_w - PADL + ww;             // wave-uniform
        const bool is_input = upd && (h == KH - 1) && (ww == PADL);
        const bool zero = (!is_input && (col < 0 || col >= LW))
                       || (!is_input && shift && h == KH - 1);
        if (zero) continue;                              // wave-uniform skip

        const int hh = shift ? h + 1 : h;                // shift => h<KH-1 here
        const float* aptr = is_input ? inrow
                                     : crow + (hh * LW + col) * FEAT;

        f32x4 x0 = *(const f32x4*)(aptr + k0);
        f32x4 x1 = *(const f32x4*)(aptr + k0 + 4);
        f32x4 x2 = *(const f32x4*)(aptr + 32 + k0);
        f32x4 x3 = *(const f32x4*)(aptr + 32 + k0 + 4);
        bf16x8 a0 = cvt8(x0, x1);
        bf16x8 a1 = cvt8(x2, x3);

        const short* wbase = Wt + p * 4096 + n * 64;     // Wt[p][f][c]
        #pragma unroll
        for (int ft = 0; ft < 4; ++ft) {
            bf16x8 b0 = *(const bf16x8*)(wbase + ft * 1024 + k0);
            bf16x8 b1 = *(const bf16x8*)(wbase + ft * 1024 + 32 + k0);
            acc[ft] = __builtin_amdgcn_mfma_f32_16x16x32_bf16(a0, b0, acc[ft], 0, 0, 0);
            acc[ft] = __builtin_amdgcn_mfma_f32_16x16x32_bf16(a1, b1, acc[ft], 0, 0, 0);
        }
    }
}

__global__ __launch_bounds__(1024) void conv_kernel(
    const float* __restrict__ inputs, const float* __restrict__ cache,
    const float* __restrict__ Wgl, const float* __restrict__ bias,
    const int* __restrict__ idxp, float* __restrict__ out,
    short* __restrict__ Wt)
{
    __shared__ float Lacc[NW][16][65];   // 66.5 KB K-split partials

    const int t    = threadIdx.x;
    const int lane = t & 63;
    const int wv   = t >> 6;             // 0..15 = K-chunk id
    const int n    = lane & 15;          // A row offset (m) and B col offset (f)
    const int g    = lane >> 4;          // k-group
    const int r0   = blockIdx.x * 16;

    const int index = idxp[0];
    int index_w = ((index % LW) + LW) % LW;
    const bool upd   = index >= 0;
    const bool shift = upd && (index_w == 0);

    // ---------------- Phase A: build masked/transposed bf16 Wt ----------------
    {
        const int e = blockIdx.x * 1024 + t;             // one element per thread
        if (e < (KH * KW) * 4096) {
            const int p  = e >> 12;
            const int e2 = e & 4095;
            const int c  = e2 >> 6, f = e2 & 63;
            const int h = p / KW, ww = p % KW;
            const bool is_input = upd && (h == KH - 1) && (ww == PADL);
            const int col = index_w - PADL + ww;
            const bool zero = (h == KH - 1 && ww >= PADL + 1)  // causal cut
                           ? (ww >= PADL + 1)                   // h==4, ww>=5
                           : false;
            const bool zero2 = (!is_input && (col < 0 || col >= LW))
                            || (!is_input && shift && h == KH - 1);
            const float val = (zero || zero2) ? 0.f : Wgl[e];
            Wt[p * 4096 + f * 64 + c] = f2bf(val);
        }
    }

    cg::this_grid().sync();

    // ---------------- Phase B: conv (R5 structure, bf16 weights) --------------
    f32x4 acc[4] = {{0,0,0,0},{0,0,0,0},{0,0,0,0},{0,0,0,0}};

    switch (wv) {
        case 0:  chunk<0 >(inputs, cache, Wt, r0, index_w, upd, shift, n, g, acc); break;
        case 1:  chunk<1 >(inputs, cache, Wt, r0, index_w, upd, shift, n, g, acc); break;
        case 2:  chunk<2 >(inputs, cache, Wt, r0, index_w, upd, shift, n, g, acc); break;
        case 3:  chunk<3 >(inputs, cache, Wt, r0, index_w, upd, shift, n, g, acc); break;
        case 4:  chunk<4 >(inputs, cache, Wt, r0, index_w, upd, shift, n, g, acc); break;
        case 5:  chunk<5 >(inputs, cache, Wt, r0, index_w, upd, shift, n, g, acc); break;
        case 6:  chunk<6 >(inputs, cache, Wt, r0, index_w, upd, shift, n, g, acc); break;
        case 7:  chunk<7 >(inputs, cache, Wt, r0, index_w, upd, shift, n, g, acc); break;
        case 8:  chunk<8 >(inputs, cache, Wt, r0, index_w, upd, shift, n, g, acc); break;
        case 9:  chunk<9 >(inputs, cache, Wt, r0, index_w, upd, shift, n, g, acc); break;
        case 10: chunk<10>(inputs, cache, Wt, r0, index_w, upd, shift, n, g, acc); break;
        case 11: chunk<11>(inputs, cache, Wt, r0, index_w, upd, shift, n, g, acc); break;
        case 12: chunk<12>(inputs, cache, Wt, r0, index_w, upd, shift, n, g, acc); break;
        case 13: chunk<13>(inputs, cache, Wt, r0, index_w, upd, shift, n, g, acc); break;
        case 14: chunk<14>(inputs, cache, Wt, r0, index_w, upd, shift, n, g, acc); break;
        default: chunk<15>(inputs, cache, Wt, r0, index_w, upd, shift, n, g, acc); break;
    }

    // D layout: col f = ft*16+n, row m = g*4+i
    #pragma unroll
    for (int ft = 0; ft < 4; ++ft)
        #pragma unroll
        for (int i = 0; i < 4; ++i)
            Lacc[wv][g * 4 + i][ft * 16 + n] = acc[ft][i];

    __syncthreads();

    // Reduce over the 16 K-chunks: thread t -> (m = wv, f = lane)
    const int m = wv;
    const int f = lane;
    float s = bias[f];
    #pragma unroll
    for (int w2 = 0; w2 < NW; ++w2) s += Lacc[w2][m][f];
    out[(long)(r0 + m) * FEAT + f] = s;
}

extern "C" void kernel_launch(void* const* d_in, const int* in_sizes, int n_in,
                              void* d_out, int out_size, void* d_ws, size_t ws_size,
                              hipStream_t stream) {
    const float* inputs = (const float*)d_in[0];
    const float* cache  = (const float*)d_in[1];
    const float* kern   = (const float*)d_in[2];
    const float* bias   = (const float*)d_in[3];
    const int*   idx    = (const int*)d_in[4];
    float* out = (float*)d_out;
    short* Wt  = (short*)d_ws;   // 45*4096*2 = 368,640 B

    void* params[] = { (void*)&inputs, (void*)&cache, (void*)&kern,
                       (void*)&bias, (void*)&idx, (void*)&out, (void*)&Wt };
    hipLaunchCooperativeKernel((void*)conv_kernel, dim3(BATCH / 16), dim3(1024),
                               params, 0, stream);
}